// Round 12
// baseline (100.177 us; speedup 1.0000x reference)
//
#include <hip/hip_runtime.h>
#include <hip/hip_bf16.h>
#include <stdint.h>

#define C_IN  256
#define C_OUT 256
#define H_IN  224
#define W_IN  224
#define HP    226
#define WP    226
#define NPIX  (H_IN * W_IN)   // 50176 = 392 * 128
#define BM    128
#define BN    128
#define BK    32              // 64 B rows -> XOR-(row&3) quad swizzle (proven optimal below)

typedef __attribute__((ext_vector_type(8))) short short8;
typedef __attribute__((ext_vector_type(4))) float f32x4;

__device__ __forceinline__ unsigned short f2bf(float f) {
    __hip_bfloat16 b = __float2bfloat16(f);
    return *(unsigned short*)&b;
}

// async global->LDS, 16B per lane; LDS dest is wave-uniform base + lane*16
__device__ __forceinline__ void gl_lds16(const unsigned short* g, unsigned short* l) {
    __builtin_amdgcn_global_load_lds(
        (const __attribute__((address_space(1))) unsigned int*)g,
        (__attribute__((address_space(3))) unsigned int*)l,
        16, 0, 0);
}

// ---------- merged prep kernel (r10-verified) ----------
// blocks [0,3584): x [C][H][W] f32 -> xp [HP][WP][C] bf16 (interior)
// blocks [3584,5888): W [O][C][3][3] f32 -> wb [p][O][C] bf16
// blocks [5888,6001): zero xp pad border
__global__ void prep_all(const float* __restrict__ x, const float* __restrict__ wk,
                         unsigned short* __restrict__ xp, unsigned short* __restrict__ wb) {
    int b = blockIdx.x;
    int t = threadIdx.x;
    if (b < 3584) {
        int ct = b & 3, wt = (b >> 2) & 3, h = b >> 4;   // 224*4*4
        int c0 = ct * 64, w0 = wt * 64;
        __shared__ float tile[64][65];
        int w   = t & 63;
        int cl0 = t >> 6;
        #pragma unroll
        for (int i = 0; i < 16; ++i) {
            int cl = i * 4 + cl0;
            float v = 0.f;
            if (w0 + w < W_IN)
                v = x[(size_t)(c0 + cl) * NPIX + (size_t)h * W_IN + w0 + w];
            tile[cl][w] = v;
        }
        __syncthreads();
        int wc = t >> 2;
        int cc = (t & 3) * 16;
        if (w0 + wc < W_IN) {
            uint32_t pk[8];
            #pragma unroll
            for (int j = 0; j < 8; ++j) {
                unsigned short lo = f2bf(tile[cc + 2 * j][wc]);
                unsigned short hi = f2bf(tile[cc + 2 * j + 1][wc]);
                pk[j] = (uint32_t)lo | ((uint32_t)hi << 16);
            }
            size_t base = ((size_t)(h + 1) * WP + (w0 + wc + 1)) * C_IN + c0 + cc;
            uint4* dst = (uint4*)(xp + base);
            dst[0] = make_uint4(pk[0], pk[1], pk[2], pk[3]);
            dst[1] = make_uint4(pk[4], pk[5], pk[6], pk[7]);
        }
        return;
    }
    if (b < 5888) {
        int idx = (b - 3584) * 256 + t;               // 9*256*256
        int c = idx & 255, o = (idx >> 8) & 255, p = idx >> 16;
        wb[((size_t)p * 256 + o) * 256 + c] = f2bf(wk[((size_t)o * 256 + c) * 9 + p]);
        return;
    }
    int i = (b - 5888) * 256 + t;                     // uint4 index
    uint4 z = make_uint4(0u, 0u, 0u, 0u);
    if (i < 7232) {
        ((uint4*)xp)[i] = z;
    } else if (i < 14464) {
        ((uint4*)(xp + (size_t)225 * WP * C_IN))[i - 7232] = z;
    } else if (i < 21632) {
        int j = i - 14464; int h = 1 + (j >> 5); int c4 = j & 31;
        ((uint4*)(xp + ((size_t)h * WP) * C_IN))[c4] = z;
    } else if (i < 28800) {
        int j = i - 21632; int h = 1 + (j >> 5); int c4 = j & 31;
        ((uint4*)(xp + ((size_t)h * WP + 225) * C_IN))[c4] = z;
    }
}

// ---------- main GEMM: out[o][n] = sum_p sum_c wb[p][o][c] * xp[...][c] ----------
// r5's proven counted-vmcnt 2-barrier body, BK=32 -> 32 KB LDS -> 4 blocks/CU
// (all 784 blocks resident; cross-block overlap hides LDS/stage/sync phases).
// Body(t): STAGE(t+1 -> buf^1)[4/wave] ; vmcnt(4) [t complete, t+1 in flight
// across barriers + compute] ; barrier ; 8x swizzled ds_read_b128 ; lgkm0 ;
// 16 MFMA (setprio) ; lgkm0 ; barrier.
// Swizzle (64 B rows, 4 quads): phys_quad = logical_quad ^ (row&3).
// Read instr: 64 lanes -> 8 lanes per 4-bank group x 4 dwords = 8-cycle
// minimum, conflict-free. Write side: source pre-swizzled with same
// involution (row within chunk = l>>2; chunks are 16 rows so row&3=(l>>2)&3).

__launch_bounds__(256, 4)
__global__ void conv_gemm(const unsigned short* __restrict__ xp,
                          const unsigned short* __restrict__ wb,
                          float* __restrict__ out) {
    // bijective XCD swizzle: 784 % 8 == 0, chunk = 98 per XCD
    int wgid = (blockIdx.x & 7) * 98 + (blockIdx.x >> 3);
    int mt = wgid & 1;
    int nt = wgid >> 1;
    int m0 = mt * BM;
    int n0 = nt * BN;
    int t  = threadIdx.x;
    int l  = t & 63, wv = t >> 6;

    // per buf: A 128x32 (4096 elems) + B 128x32 (4096) ; 2 bufs = 32 KB
    __shared__ __align__(16) unsigned short lds[2 * 8192];

    // ---- staging: 8 chunks of 16 rows (1 KB) per matrix; wave wv owns
    // chunks 2wv, 2wv+1. lane l -> row_in_chunk = l>>2, phys quad = l&3,
    // logical quad = (l&3) ^ (row&3) = (l&3) ^ ((l>>2)&3).
    int lq8 = ((l & 3) ^ ((l >> 2) & 3)) * 8;
    int offA0, offA1, offB0, offB1;
    {
        int r0 = (2 * wv + 0) * 16 + (l >> 2);   // 0..127
        int r1 = r0 + 16;
        offA0 = (m0 + r0) * C_IN + lq8;
        offA1 = (m0 + r1) * C_IN + lq8;
        int nc0 = n0 + r0, nc1 = n0 + r1;
        int h0 = nc0 / W_IN, h1 = nc1 / W_IN;
        offB0 = (h0 * WP + (nc0 - h0 * W_IN)) * C_IN + lq8;
        offB1 = (h1 * WP + (nc1 - h1 * W_IN)) * C_IN + lq8;
    }

    // ---- read-side fragment addressing ----
    int la = l & 15;
    int lk = l >> 4;                    // logical k-quad 0..3 (k = lk*8)
    int mo = (wv >> 1) * 64;
    int no = (wv & 1) * 64;
    int xq = (lk ^ (la & 3)) * 8;       // phys quad for ds_read (row&3 = la&3)

    f32x4 acc[4][4];
    #pragma unroll
    for (int i = 0; i < 4; ++i)
        #pragma unroll
        for (int j = 0; j < 4; ++j)
            acc[i][j] = f32x4{0.f, 0.f, 0.f, 0.f};

#define STAGE(BD, S) do {                                                    \
    int s_ = (S);                                                            \
    int p_ = s_ >> 3, cs_ = (s_ & 7) << 5;                                   \
    int kh_ = (p_ * 11) >> 5; int kw_ = p_ - 3 * kh_;                        \
    const unsigned short* aS_ = wb + p_ * 65536 + cs_;                       \
    const unsigned short* bS_ = xp + (kh_ * WP + kw_) * C_IN + cs_;          \
    gl_lds16(aS_ + offA0, &lds[(BD) * 8192 + (2 * wv + 0) * 512]);           \
    gl_lds16(aS_ + offA1, &lds[(BD) * 8192 + (2 * wv + 1) * 512]);           \
    gl_lds16(bS_ + offB0, &lds[(BD) * 8192 + 4096 + (2 * wv + 0) * 512]);    \
    gl_lds16(bS_ + offB1, &lds[(BD) * 8192 + 4096 + (2 * wv + 1) * 512]);    \
} while (0)

#define COMPUTE(BC) do {                                                     \
    short8 af_[4], bf_[4];                                                   \
    _Pragma("unroll")                                                        \
    for (int i_ = 0; i_ < 4; ++i_)                                           \
        af_[i_] = *(const short8*)&lds[(BC) * 8192 + (mo + i_ * 16 + la) * BK + xq]; \
    _Pragma("unroll")                                                        \
    for (int i_ = 0; i_ < 4; ++i_)                                           \
        bf_[i_] = *(const short8*)&lds[(BC) * 8192 + 4096 + (no + i_ * 16 + la) * BK + xq]; \
    asm volatile("s_waitcnt lgkmcnt(0)" ::: "memory");                       \
    __builtin_amdgcn_sched_barrier(0);                                       \
    __builtin_amdgcn_s_setprio(1);                                           \
    _Pragma("unroll")                                                        \
    for (int i_ = 0; i_ < 4; ++i_)                                           \
        _Pragma("unroll")                                                    \
        for (int j_ = 0; j_ < 4; ++j_)                                       \
            acc[i_][j_] = __builtin_amdgcn_mfma_f32_16x16x32_bf16(           \
                af_[i_], bf_[j_], acc[i_][j_], 0, 0, 0);                     \
    __builtin_amdgcn_s_setprio(0);                                           \
} while (0)

#define BODY(BC, S, DO_STAGE) do {                                           \
    if (DO_STAGE) STAGE((BC) ^ 1, (S) + 1);                                  \
    asm volatile("s_waitcnt vmcnt(%0)" :: "i"((DO_STAGE) ? 4 : 0) : "memory"); \
    __builtin_amdgcn_sched_barrier(0);                                       \
    __builtin_amdgcn_s_barrier();                                            \
    __builtin_amdgcn_sched_barrier(0);                                       \
    COMPUTE(BC);                                                             \
    asm volatile("s_waitcnt lgkmcnt(0)" ::: "memory");                       \
    __builtin_amdgcn_sched_barrier(0);                                       \
    __builtin_amdgcn_s_barrier();                                            \
    __builtin_amdgcn_sched_barrier(0);                                       \
} while (0)

    // 72 K-steps total (9 taps x 8 c-slices of 32)
    STAGE(0, 0);
    #pragma unroll 1
    for (int k = 0; k < 35; ++k) {      // s = 0..69
        BODY(0, 2 * k, 1);
        BODY(1, 2 * k + 1, 1);
    }
    BODY(0, 70, 1);                     // stages s=71 into buf1
    BODY(1, 71, 0);                     // final, drains all

#undef BODY
#undef COMPUTE
#undef STAGE

    // epilogue: D frag col = l&15 (n), row = (l>>4)*4 + r (o)
    int ro = lk * 4;
    #pragma unroll
    for (int i = 0; i < 4; ++i) {
        #pragma unroll
        for (int j = 0; j < 4; ++j) {
            int oo = m0 + mo + i * 16 + ro;
            int nn = n0 + no + j * 16 + la;
            #pragma unroll
            for (int r = 0; r < 4; ++r)
                out[(size_t)(oo + r) * NPIX + nn] = acc[i][j][r];
        }
    }
}

// ---------- fallback (tiny ws): naive direct conv, correct but slow ----------
__global__ void conv_naive(const float* __restrict__ x, const float* __restrict__ wk,
                           float* __restrict__ out) {
    int idx = blockIdx.x * 256 + threadIdx.x;   // o*NPIX + n
    int n = idx % NPIX;
    int o = idx / NPIX;
    int h = n / W_IN, w = n - (n / W_IN) * W_IN;
    float s = 0.f;
    for (int c = 0; c < C_IN; ++c) {
        const float* xc = x + (size_t)c * NPIX;
        const float* wc = wk + ((size_t)o * C_IN + c) * 9;
        #pragma unroll
        for (int kh = 0; kh < 3; ++kh) {
            int hh = h + kh - 1;
            if (hh < 0 || hh >= H_IN) continue;
            #pragma unroll
            for (int kw = 0; kw < 3; ++kw) {
                int ww = w + kw - 1;
                if (ww < 0 || ww >= W_IN) continue;
                s += xc[hh * W_IN + ww] * wc[kh * 3 + kw];
            }
        }
    }
    out[idx] = s;
}

extern "C" void kernel_launch(void* const* d_in, const int* in_sizes, int n_in,
                              void* d_out, int out_size, void* d_ws, size_t ws_size,
                              hipStream_t stream) {
    const float* x  = (const float*)d_in[0];
    const float* wk = (const float*)d_in[1];
    float* out = (float*)d_out;

    const size_t xp_elems = (size_t)HP * WP * C_IN;   // 13,075,456
    const size_t wb_elems = (size_t)9 * 256 * 256;    // 589,824
    const size_t need = (xp_elems + wb_elems) * 2;    // ~27.3 MB

    if (ws_size < need) {
        conv_naive<<<(C_OUT * NPIX) / 256, 256, 0, stream>>>(x, wk, out);
        return;
    }

    unsigned short* xp = (unsigned short*)d_ws;
    unsigned short* wb = xp + xp_elems;

    prep_all<<<3584 + 2304 + 113, 256, 0, stream>>>(x, wk, xp, wb);
    conv_gemm<<<392 * 2, 256, 0, stream>>>(xp, wb, out);
}

// Round 13
// 81.248 us; speedup vs baseline: 1.2330x; 1.2330x over previous
//
#include <hip/hip_runtime.h>
#include <hip/hip_bf16.h>
#include <stdint.h>

#define C_IN  256
#define C_OUT 256
#define H_IN  224
#define W_IN  224
#define HP    226
#define WP    226
#define NPIX  (H_IN * W_IN)   // 50176 = 392 * 128
#define BM    128
#define BN    128
#define BK    64              // 128 B rows -> XOR-(row&7) swizzle: 0 conflicts (r2/r5/r9/r10/r11)
                              // NOTE: BK=32 (64 B rows) is structurally +4cyc/ds_read_b128 (r4, r12)

typedef __attribute__((ext_vector_type(8))) short short8;
typedef __attribute__((ext_vector_type(4))) float f32x4;

__device__ __forceinline__ unsigned short f2bf(float f) {
    __hip_bfloat16 b = __float2bfloat16(f);
    return *(unsigned short*)&b;
}

// async global->LDS, 16B per lane; LDS dest is wave-uniform base + lane*16
__device__ __forceinline__ void gl_lds16(const unsigned short* g, unsigned short* l) {
    __builtin_amdgcn_global_load_lds(
        (const __attribute__((address_space(1))) unsigned int*)g,
        (__attribute__((address_space(3))) unsigned int*)l,
        16, 0, 0);
}

// ---------- merged prep kernel (r10/r12-verified) ----------
// blocks [0,3584): x [C][H][W] f32 -> xp [HP][WP][C] bf16 (interior)
// blocks [3584,5888): W [O][C][3][3] f32 -> wb [p][O][C] bf16
// blocks [5888,6001): zero xp pad border
__global__ void prep_all(const float* __restrict__ x, const float* __restrict__ wk,
                         unsigned short* __restrict__ xp, unsigned short* __restrict__ wb) {
    int b = blockIdx.x;
    int t = threadIdx.x;
    if (b < 3584) {
        int ct = b & 3, wt = (b >> 2) & 3, h = b >> 4;   // 224*4*4
        int c0 = ct * 64, w0 = wt * 64;
        __shared__ float tile[64][65];
        int w   = t & 63;
        int cl0 = t >> 6;
        #pragma unroll
        for (int i = 0; i < 16; ++i) {
            int cl = i * 4 + cl0;
            float v = 0.f;
            if (w0 + w < W_IN)
                v = x[(size_t)(c0 + cl) * NPIX + (size_t)h * W_IN + w0 + w];
            tile[cl][w] = v;
        }
        __syncthreads();
        int wc = t >> 2;
        int cc = (t & 3) * 16;
        if (w0 + wc < W_IN) {
            uint32_t pk[8];
            #pragma unroll
            for (int j = 0; j < 8; ++j) {
                unsigned short lo = f2bf(tile[cc + 2 * j][wc]);
                unsigned short hi = f2bf(tile[cc + 2 * j + 1][wc]);
                pk[j] = (uint32_t)lo | ((uint32_t)hi << 16);
            }
            size_t base = ((size_t)(h + 1) * WP + (w0 + wc + 1)) * C_IN + c0 + cc;
            uint4* dst = (uint4*)(xp + base);
            dst[0] = make_uint4(pk[0], pk[1], pk[2], pk[3]);
            dst[1] = make_uint4(pk[4], pk[5], pk[6], pk[7]);
        }
        return;
    }
    if (b < 5888) {
        int idx = (b - 3584) * 256 + t;               // 9*256*256
        int c = idx & 255, o = (idx >> 8) & 255, p = idx >> 16;
        wb[((size_t)p * 256 + o) * 256 + c] = f2bf(wk[((size_t)o * 256 + c) * 9 + p]);
        return;
    }
    int i = (b - 5888) * 256 + t;                     // uint4 index
    uint4 z = make_uint4(0u, 0u, 0u, 0u);
    if (i < 7232) {
        ((uint4*)xp)[i] = z;
    } else if (i < 14464) {
        ((uint4*)(xp + (size_t)225 * WP * C_IN))[i - 7232] = z;
    } else if (i < 21632) {
        int j = i - 14464; int h = 1 + (j >> 5); int c4 = j & 31;
        ((uint4*)(xp + ((size_t)h * WP) * C_IN))[c4] = z;
    } else if (i < 28800) {
        int j = i - 21632; int h = 1 + (j >> 5); int c4 = j & 31;
        ((uint4*)(xp + ((size_t)h * WP + 225) * C_IN))[c4] = z;
    }
}

// ---------- main GEMM: out[o][n] = sum_p sum_c wb[p][o][c] * xp[...][c] ----------
// r5-verbatim (session best: 70.5 us GEMM, MfmaUtil 34.6, 0 conflicts).
// Minimum-2-phase counted-vmcnt pipeline (catalog T3/T4 recipe):
//   STAGE(buf^1, t+1) -> vmcnt(8) (t+1's 8 loads stay in flight across barrier)
//   -> barrier -> COMPUTE(buf) (16 ds_read_b128 + 32 MFMA) -> lgkm(0) -> barrier.
// LDS: 2 bufs x (A 128x64 + B 128x64) bf16 = 64 KB -> 2 blocks/CU; cross-block
// overlap (m114) hides the barrier/wait phases.
// Swizzle (verified 0-conflict): phys_quad = logical_quad ^ (row & 7), write
// side via pre-swizzled global source, read side via XOR'd ds_read offset.

__launch_bounds__(256, 2)
__global__ void conv_gemm(const unsigned short* __restrict__ xp,
                          const unsigned short* __restrict__ wb,
                          float* __restrict__ out) {
    // bijective XCD swizzle: 784 % 8 == 0, chunk = 98 per XCD
    int wgid = (blockIdx.x & 7) * 98 + (blockIdx.x >> 3);
    int mt = wgid & 1;
    int nt = wgid >> 1;
    int m0 = mt * BM;
    int n0 = nt * BN;
    int t  = threadIdx.x;
    int l  = t & 63, wv = t >> 6;

    __shared__ __align__(16) unsigned short lds[2 * 16384];   // 64 KB

    // ---- staging: per matrix 16 chunks of 8 rows (1 KB each); wave wv owns
    // chunks 4wv..4wv+3 of A and of B. lane l -> row_in_chunk = l>>3,
    // phys quad = l&7, logical quad q = (l&7) ^ (row&7) = (l&7) ^ (l>>3).
    int q8 = ((l & 7) ^ (l >> 3)) * 8;
    int rA = l >> 3;
    int offA0, offA1, offA2, offA3, offB0, offB1, offB2, offB3;
    {
        int r0 = (wv * 4 + 0) * 8 + rA;
        int r1 = (wv * 4 + 1) * 8 + rA;
        int r2 = (wv * 4 + 2) * 8 + rA;
        int r3 = (wv * 4 + 3) * 8 + rA;
        offA0 = (m0 + r0) * C_IN + q8;
        offA1 = (m0 + r1) * C_IN + q8;
        offA2 = (m0 + r2) * C_IN + q8;
        offA3 = (m0 + r3) * C_IN + q8;
        int nc0 = n0 + r0, nc1 = n0 + r1, nc2 = n0 + r2, nc3 = n0 + r3;
        int h0 = nc0 / W_IN, h1 = nc1 / W_IN, h2 = nc2 / W_IN, h3 = nc3 / W_IN;
        offB0 = (h0 * WP + (nc0 - h0 * W_IN)) * C_IN + q8;
        offB1 = (h1 * WP + (nc1 - h1 * W_IN)) * C_IN + q8;
        offB2 = (h2 * WP + (nc2 - h2 * W_IN)) * C_IN + q8;
        offB3 = (h3 * WP + (nc3 - h3 * W_IN)) * C_IN + q8;
    }

    // ---- read-side fragment addressing ----
    int la = l & 15;
    int lk = l >> 4;                    // k sub-quad 0..3
    int mo = (wv >> 1) * 64;
    int no = (wv & 1) * 64;
    // k-slice ks: logical quad = ks*4 + lk; phys = logical ^ (row&7), row&7 = la&7
    int xq0 = ((0 * 4 + lk) ^ (la & 7)) * 8;
    int xq1 = ((1 * 4 + lk) ^ (la & 7)) * 8;

    f32x4 acc[4][4];
    #pragma unroll
    for (int i = 0; i < 4; ++i)
        #pragma unroll
        for (int j = 0; j < 4; ++j)
            acc[i][j] = f32x4{0.f, 0.f, 0.f, 0.f};

#define STAGE(BD, S) do {                                                    \
    int s_ = (S);                                                            \
    int p_ = s_ >> 2, cs_ = (s_ & 3) << 6;                                   \
    int kh_ = (p_ * 11) >> 5; int kw_ = p_ - 3 * kh_;                        \
    const unsigned short* aS_ = wb + p_ * 65536 + cs_;                       \
    const unsigned short* bS_ = xp + (kh_ * WP + kw_) * C_IN + cs_;          \
    gl_lds16(aS_ + offA0, &lds[(BD) * 16384 + (wv * 4 + 0) * 512]);          \
    gl_lds16(aS_ + offA1, &lds[(BD) * 16384 + (wv * 4 + 1) * 512]);          \
    gl_lds16(aS_ + offA2, &lds[(BD) * 16384 + (wv * 4 + 2) * 512]);          \
    gl_lds16(aS_ + offA3, &lds[(BD) * 16384 + (wv * 4 + 3) * 512]);          \
    gl_lds16(bS_ + offB0, &lds[(BD) * 16384 + 8192 + (wv * 4 + 0) * 512]);   \
    gl_lds16(bS_ + offB1, &lds[(BD) * 16384 + 8192 + (wv * 4 + 1) * 512]);   \
    gl_lds16(bS_ + offB2, &lds[(BD) * 16384 + 8192 + (wv * 4 + 2) * 512]);   \
    gl_lds16(bS_ + offB3, &lds[(BD) * 16384 + 8192 + (wv * 4 + 3) * 512]);   \
} while (0)

#define COMPUTE(BC) do {                                                     \
    short8 af_[4][2], bf_[4][2];                                             \
    _Pragma("unroll")                                                        \
    for (int i_ = 0; i_ < 4; ++i_) {                                         \
        af_[i_][0] = *(const short8*)&lds[(BC) * 16384 + (mo + i_ * 16 + la) * BK + xq0]; \
        af_[i_][1] = *(const short8*)&lds[(BC) * 16384 + (mo + i_ * 16 + la) * BK + xq1]; \
    }                                                                        \
    _Pragma("unroll")                                                        \
    for (int i_ = 0; i_ < 4; ++i_) {                                         \
        bf_[i_][0] = *(const short8*)&lds[(BC) * 16384 + 8192 + (no + i_ * 16 + la) * BK + xq0]; \
        bf_[i_][1] = *(const short8*)&lds[(BC) * 16384 + 8192 + (no + i_ * 16 + la) * BK + xq1]; \
    }                                                                        \
    __builtin_amdgcn_s_setprio(1);                                           \
    _Pragma("unroll")                                                        \
    for (int i_ = 0; i_ < 4; ++i_)                                           \
        _Pragma("unroll")                                                    \
        for (int j_ = 0; j_ < 4; ++j_)                                       \
            acc[i_][j_] = __builtin_amdgcn_mfma_f32_16x16x32_bf16(           \
                af_[i_][0], bf_[j_][0], acc[i_][j_], 0, 0, 0);               \
    _Pragma("unroll")                                                        \
    for (int i_ = 0; i_ < 4; ++i_)                                           \
        _Pragma("unroll")                                                    \
        for (int j_ = 0; j_ < 4; ++j_)                                       \
            acc[i_][j_] = __builtin_amdgcn_mfma_f32_16x16x32_bf16(           \
                af_[i_][1], bf_[j_][1], acc[i_][j_], 0, 0, 0);               \
    __builtin_amdgcn_s_setprio(0);                                           \
} while (0)

#define GUARD_IN(VMSTR) do {                                                 \
    asm volatile("s_waitcnt " VMSTR ::: "memory");                           \
    __builtin_amdgcn_sched_barrier(0);                                       \
    __builtin_amdgcn_s_barrier();                                            \
    __builtin_amdgcn_sched_barrier(0);                                       \
} while (0)

#define GUARD_OUT() do {                                                     \
    asm volatile("s_waitcnt lgkmcnt(0)" ::: "memory");                       \
    __builtin_amdgcn_sched_barrier(0);                                       \
    __builtin_amdgcn_s_barrier();                                            \
    __builtin_amdgcn_sched_barrier(0);                                       \
} while (0)

#define BODY(BC, S) do {                                                     \
    STAGE((BC) ^ 1, (S) + 1);                                                \
    GUARD_IN("vmcnt(8)");                                                    \
    COMPUTE(BC);                                                             \
    GUARD_OUT();                                                             \
} while (0)

    // 36 K-steps total (9 taps x 4 c-slices of 64)
    STAGE(0, 0);
    #pragma unroll 1
    for (int k = 0; k < 17; ++k) {      // computes s = 0..33
        BODY(0, 2 * k);
        BODY(1, 2 * k + 1);
    }
    BODY(0, 34);                        // computes 34, stages 35 into buf1
    GUARD_IN("vmcnt(0)");               // s=35 ready
    COMPUTE(1);                         // final step, no trailing guard

#undef BODY
#undef GUARD_OUT
#undef GUARD_IN
#undef COMPUTE
#undef STAGE

    // epilogue: D frag col = l&15 (n), row = (l>>4)*4 + r (o)
    int ro = lk * 4;
    #pragma unroll
    for (int i = 0; i < 4; ++i) {
        #pragma unroll
        for (int j = 0; j < 4; ++j) {
            int oo = m0 + mo + i * 16 + ro;
            int nn = n0 + no + j * 16 + la;
            #pragma unroll
            for (int r = 0; r < 4; ++r)
                out[(size_t)(oo + r) * NPIX + nn] = acc[i][j][r];
        }
    }
}

// ---------- fallback (tiny ws): naive direct conv, correct but slow ----------
__global__ void conv_naive(const float* __restrict__ x, const float* __restrict__ wk,
                           float* __restrict__ out) {
    int idx = blockIdx.x * 256 + threadIdx.x;   // o*NPIX + n
    int n = idx % NPIX;
    int o = idx / NPIX;
    int h = n / W_IN, w = n - (n / W_IN) * W_IN;
    float s = 0.f;
    for (int c = 0; c < C_IN; ++c) {
        const float* xc = x + (size_t)c * NPIX;
        const float* wc = wk + ((size_t)o * C_IN + c) * 9;
        #pragma unroll
        for (int kh = 0; kh < 3; ++kh) {
            int hh = h + kh - 1;
            if (hh < 0 || hh >= H_IN) continue;
            #pragma unroll
            for (int kw = 0; kw < 3; ++kw) {
                int ww = w + kw - 1;
                if (ww < 0 || ww >= W_IN) continue;
                s += xc[hh * W_IN + ww] * wc[kh * 3 + kw];
            }
        }
    }
    out[idx] = s;
}

extern "C" void kernel_launch(void* const* d_in, const int* in_sizes, int n_in,
                              void* d_out, int out_size, void* d_ws, size_t ws_size,
                              hipStream_t stream) {
    const float* x  = (const float*)d_in[0];
    const float* wk = (const float*)d_in[1];
    float* out = (float*)d_out;

    const size_t xp_elems = (size_t)HP * WP * C_IN;   // 13,075,456
    const size_t wb_elems = (size_t)9 * 256 * 256;    // 589,824
    const size_t need = (xp_elems + wb_elems) * 2;    // ~27.3 MB

    if (ws_size < need) {
        conv_naive<<<(C_OUT * NPIX) / 256, 256, 0, stream>>>(x, wk, out);
        return;
    }

    unsigned short* xp = (unsigned short*)d_ws;
    unsigned short* wb = xp + xp_elems;

    prep_all<<<3584 + 2304 + 113, 256, 0, stream>>>(x, wk, xp, wb);
    conv_gemm<<<392 * 2, 256, 0, stream>>>(xp, wb, out);
}